// Round 1
// baseline (100.171 us; speedup 1.0000x reference)
//
#include <hip/hip_runtime.h>
#include <math.h>

// ---------- helpers ----------
__device__ __forceinline__ float eluf(float v) {
    return v > 0.f ? v : (__expf(v) - 1.f);
}
__device__ __forceinline__ float sigmf(float u) {
    return 1.f / (1.f + __expf(-u));
}
__device__ __forceinline__ float bnscale(float g) {
    return g / sqrtf(1.0f + 1e-5f);
}

__device__ __forceinline__ float block_sum(float v, float* red) {
    int tid = threadIdx.x;
    red[tid] = v;
    __syncthreads();
    for (int s = 128; s > 0; s >>= 1) {
        if (tid < s) red[tid] += red[tid + s];
        __syncthreads();
    }
    float r = red[0];
    __syncthreads();
    return r;
}

// ---------- kernel 1: stem conv2d(2x3,'same') + BN + ELU + spatial depthwise reduce over 22 rows ----------
// x: (256,1,22,1000)  -> pre: (256,15,1000)
__global__ __launch_bounds__(256) void k_stem_spatial(
    const float* __restrict__ x,
    const float* __restrict__ stem_w,  // (15,1,2,3)
    const float* __restrict__ stem_g, const float* __restrict__ stem_b,
    const float* __restrict__ sw1, const float* __restrict__ sw2, const float* __restrict__ sw3, // (5,22) each
    float* __restrict__ pre)
{
    __shared__ float xs[23 * 258];   // rows 0..21 from x, row 22 = H zero-pad; cols t0-1 .. t0+256
    const int b = blockIdx.y;
    const int t0 = blockIdx.x * 256;
    const int tid = threadIdx.x;
    const float* xb = x + b * 22 * 1000;

    for (int idx = tid; idx < 23 * 258; idx += 256) {
        int r = idx / 258, c = idx % 258;
        int gt = t0 + c - 1;
        float v = 0.f;
        if (r < 22 && gt >= 0 && gt < 1000) v = xb[r * 1000 + gt];
        xs[idx] = v;
    }
    __syncthreads();

    const int t = t0 + tid;
    if (t >= 1000) return;

    // per-thread register copy of the 23x3 x-window
    float xa[23], xm[23], xc[23];
#pragma unroll
    for (int i = 0; i < 23; ++i) {
        xa[i] = xs[i * 258 + tid];
        xm[i] = xs[i * 258 + tid + 1];
        xc[i] = xs[i * 258 + tid + 2];
    }

    for (int C = 0; C < 15; ++C) {
        const float w00 = stem_w[C * 6 + 0], w01 = stem_w[C * 6 + 1], w02 = stem_w[C * 6 + 2];
        const float w10 = stem_w[C * 6 + 3], w11 = stem_w[C * 6 + 4], w12 = stem_w[C * 6 + 5];
        const float gs = bnscale(stem_g[C]);
        const float bs = stem_b[C];
        const float* swp = (C < 5 ? sw1 : (C < 10 ? sw2 : sw3)) + (C % 5) * 22;
        float acc = 0.f;
#pragma unroll
        for (int i = 0; i < 22; ++i) {
            float v = w00 * xa[i]     + w01 * xm[i]     + w02 * xc[i]
                    + w10 * xa[i + 1] + w11 * xm[i + 1] + w12 * xc[i + 1];
            v = v * gs + bs;
            v = eluf(v);
            acc += v * swp[i];
        }
        pre[(b * 15 + C) * 1000 + t] = acc;
    }
}

// ---------- kernel 2: per (b,C) row: BN1+ELU+SimAM -> temporal depthwise conv -> BN2+ELU+SimAM -> pool 1000->40 ----------
#define PAD 32
__global__ __launch_bounds__(256) void k_branch_row(
    const float* __restrict__ pre,
    const float* __restrict__ g1a, const float* __restrict__ b1a,
    const float* __restrict__ tw1,
    const float* __restrict__ g2a, const float* __restrict__ b2a,
    const float* __restrict__ g1b, const float* __restrict__ b1b,
    const float* __restrict__ tw2,
    const float* __restrict__ g2b, const float* __restrict__ b2b,
    const float* __restrict__ g1c, const float* __restrict__ b1c,
    const float* __restrict__ tw3,
    const float* __restrict__ g2c, const float* __restrict__ b2c,
    float* __restrict__ pooled)   // (256,15,40)
{
    __shared__ float ybuf[1000];
    __shared__ float zbuf[1000 + 2 * PAD];
    __shared__ float red[256];

    const int bid = blockIdx.x;
    const int b = bid / 15, C = bid % 15;
    const int br = C / 5, c = C % 5;
    const int tid = threadIdx.x;

    const float* g1p = br == 0 ? g1a : br == 1 ? g1b : g1c;
    const float* b1p = br == 0 ? b1a : br == 1 ? b1b : b1c;
    const float* g2p = br == 0 ? g2a : br == 1 ? g2b : g2c;
    const float* b2p = br == 0 ? b2a : br == 1 ? b2b : b2c;
    const int kt = br == 0 ? 15 : br == 1 ? 31 : 63;
    const float* twp = (br == 0 ? tw1 : br == 1 ? tw2 : tw3) + c * kt;

    const float g1s = bnscale(g1p[c]), b1v = b1p[c];
    const float g2s = bnscale(g2p[c]), b2v = b2p[c];
    const float* row = pre + (b * 15 + C) * 1000;

    // BN1 + ELU
    float part = 0.f;
    for (int t = tid; t < 1000; t += 256) {
        float v = row[t] * g1s + b1v;
        v = eluf(v);
        ybuf[t] = v;
        part += v;
    }
    const float mu1 = block_sum(part, red) * (1.f / 1000.f);
    part = 0.f;
    for (int t = tid; t < 1000; t += 256) { float d = ybuf[t] - mu1; part += d * d; }
    const float var1 = block_sum(part, red) * (1.f / 1000.f);
    const float iv1 = 1.f / (2.f * var1 + 1e-12f);

    // SimAM -> z (zero-padded for conv)
    if (tid < PAD) { zbuf[tid] = 0.f; zbuf[PAD + 1000 + tid] = 0.f; }
    for (int t = tid; t < 1000; t += 256) {
        float y = ybuf[t];
        float d = y - mu1;
        float e = d * d * iv1 + 1e-4f;
        zbuf[PAD + t] = sigmf(1.f / (e + 1e-12f)) * y;
    }
    __syncthreads();

    // temporal depthwise conv, 'same'
    const int pad = kt >> 1;
    part = 0.f;
    for (int t = tid; t < 1000; t += 256) {
        float acc = 0.f;
        const float* zp = &zbuf[PAD + t - pad];
        for (int d = 0; d < kt; ++d) acc += zp[d] * twp[d];
        float v = acc * g2s + b2v;
        v = eluf(v);
        ybuf[t] = v;
        part += v;
    }
    const float mu2 = block_sum(part, red) * (1.f / 1000.f);
    part = 0.f;
    for (int t = tid; t < 1000; t += 256) { float d = ybuf[t] - mu2; part += d * d; }
    const float var2 = block_sum(part, red) * (1.f / 1000.f);
    const float iv2 = 1.f / (2.f * var2 + 1e-12f);

    for (int t = tid; t < 1000; t += 256) {
        float u = ybuf[t];
        float d = u - mu2;
        float e = d * d * iv2 + 1e-4f;
        zbuf[PAD + t] = sigmf(1.f / (e + 1e-12f)) * u;
    }
    __syncthreads();

    // adaptive pool 1000 -> 40 (uniform windows of 25)
    if (tid < 40) {
        float s = 0.f;
        for (int j = 0; j < 25; ++j) s += zbuf[PAD + tid * 25 + j];
        pooled[(b * 15 + C) * 40 + tid] = s * (1.f / 25.f);
    }
}

// ---------- kernel 3: head (per batch): pointwise+BN+ELU+SimAM -> deform1 -> deform2 -> pool 27->25 -> FC ----------
__global__ __launch_bounds__(64) void k_head(
    const float* __restrict__ pooled,   // (256,15,40)
    const float* __restrict__ pw_w, const float* __restrict__ pw_g, const float* __restrict__ pw_b,
    const float* __restrict__ d1_w, const float* __restrict__ d1_ow, const float* __restrict__ d1_ob,
    const float* __restrict__ d2_w, const float* __restrict__ d2_ow, const float* __restrict__ d2_ob,
    const float* __restrict__ fc_w, const float* __restrict__ fc_b,
    float* __restrict__ out)            // (256,4)
{
    __shared__ float P[600];     // 15x40
    __shared__ float A[200];     // 5x40
    __shared__ float Bv[200];    // 5x40
    __shared__ float C1[180];    // 5x36
    __shared__ float C2[135];    // 5x27
    __shared__ float D[125];     // 5x25
    __shared__ float mu5[5], iv5[5];

    const int b = blockIdx.x, tid = threadIdx.x;

    for (int i = tid; i < 600; i += 64) P[i] = pooled[b * 600 + i];
    __syncthreads();

    // pointwise 15->5 + BN + ELU
    for (int i = tid; i < 200; i += 64) {
        int o = i / 40, t = i % 40;
        float s = 0.f;
        for (int c = 0; c < 15; ++c) s += P[c * 40 + t] * pw_w[o * 15 + c];
        float v = s * bnscale(pw_g[o]) + pw_b[o];
        A[i] = eluf(v);
    }
    __syncthreads();

    if (tid < 5) {
        float s = 0.f;
        for (int t = 0; t < 40; ++t) s += A[tid * 40 + t];
        float mu = s * (1.f / 40.f);
        float v2 = 0.f;
        for (int t = 0; t < 40; ++t) { float d = A[tid * 40 + t] - mu; v2 += d * d; }
        mu5[tid] = mu;
        iv5[tid] = 1.f / (2.f * (v2 * (1.f / 40.f)) + 1e-12f);
    }
    __syncthreads();

    for (int i = tid; i < 200; i += 64) {
        int o = i / 40;
        float a = A[i];
        float d = a - mu5[o];
        float e = d * d * iv5[o] + 1e-4f;
        Bv[i] = sigmf(1.f / (e + 1e-12f)) * a;
    }
    __syncthreads();

    // deformable conv 1: T=40, K=5, Tout=36
    for (int i = tid; i < 180; i += 64) {
        int c = i / 36, t = i % 36;
        float o = 0.f;
        for (int k = 0; k < 5; ++k) {
            float off = d1_ob[c * 5 + k];
            for (int d = 0; d < 5; ++d) off += Bv[c * 40 + t + d] * d1_ow[(c * 5 + k) * 5 + d];
            float pos = (float)(t + k) + off;
            float fl = floorf(pos);
            float f = pos - fl;
            int i0 = (int)fl;
            float v0 = (i0 >= 0 && i0 < 40) ? Bv[c * 40 + i0] : 0.f;
            float v1 = (i0 + 1 >= 0 && i0 + 1 < 40) ? Bv[c * 40 + i0 + 1] : 0.f;
            o += (v0 * (1.f - f) + v1 * f) * d1_w[c * 5 + k];
        }
        C1[i] = o;
    }
    __syncthreads();

    // deformable conv 2: T=36, K=10, Tout=27
    for (int i = tid; i < 135; i += 64) {
        int c = i / 27, t = i % 27;
        float o = 0.f;
        for (int k = 0; k < 10; ++k) {
            float off = d2_ob[c * 10 + k];
            for (int d = 0; d < 10; ++d) off += C1[c * 36 + t + d] * d2_ow[(c * 10 + k) * 10 + d];
            float pos = (float)(t + k) + off;
            float fl = floorf(pos);
            float f = pos - fl;
            int i0 = (int)fl;
            float v0 = (i0 >= 0 && i0 < 36) ? C1[c * 36 + i0] : 0.f;
            float v1 = (i0 + 1 >= 0 && i0 + 1 < 36) ? C1[c * 36 + i0 + 1] : 0.f;
            o += (v0 * (1.f - f) + v1 * f) * d2_w[c * 10 + k];
        }
        C2[i] = o;
    }
    __syncthreads();

    // adaptive pool 27 -> 25
    for (int i = tid; i < 125; i += 64) {
        int c = i / 25, j = i % 25;
        int s0 = (j * 27) / 25;
        int e0 = ((j + 1) * 27 + 24) / 25;
        float s = 0.f;
        for (int q = s0; q < e0; ++q) s += C2[c * 27 + q];
        D[i] = s / (float)(e0 - s0);
    }
    __syncthreads();

    // FC (4,125)
    if (tid < 4) {
        float s = fc_b[tid];
        for (int i = 0; i < 125; ++i) s += D[i] * fc_w[tid * 125 + i];
        out[b * 4 + tid] = s;
    }
}

extern "C" void kernel_launch(void* const* d_in, const int* in_sizes, int n_in,
                              void* d_out, int out_size, void* d_ws, size_t ws_size,
                              hipStream_t stream) {
    const float* x      = (const float*)d_in[0];
    const float* stem_w = (const float*)d_in[1];
    const float* stem_g = (const float*)d_in[2];
    const float* stem_b = (const float*)d_in[3];
    const float* b1_sw = (const float*)d_in[4];
    const float* b1_g1 = (const float*)d_in[5];
    const float* b1_b1 = (const float*)d_in[6];
    const float* b1_tw = (const float*)d_in[7];
    const float* b1_g2 = (const float*)d_in[8];
    const float* b1_b2 = (const float*)d_in[9];
    const float* b2_sw = (const float*)d_in[10];
    const float* b2_g1 = (const float*)d_in[11];
    const float* b2_b1 = (const float*)d_in[12];
    const float* b2_tw = (const float*)d_in[13];
    const float* b2_g2 = (const float*)d_in[14];
    const float* b2_b2 = (const float*)d_in[15];
    const float* b3_sw = (const float*)d_in[16];
    const float* b3_g1 = (const float*)d_in[17];
    const float* b3_b1 = (const float*)d_in[18];
    const float* b3_tw = (const float*)d_in[19];
    const float* b3_g2 = (const float*)d_in[20];
    const float* b3_b2 = (const float*)d_in[21];
    const float* pw_w  = (const float*)d_in[22];
    const float* pw_g  = (const float*)d_in[23];
    const float* pw_b  = (const float*)d_in[24];
    const float* d1_w  = (const float*)d_in[25];
    const float* d1_ow = (const float*)d_in[26];
    const float* d1_ob = (const float*)d_in[27];
    const float* d2_w  = (const float*)d_in[28];
    const float* d2_ow = (const float*)d_in[29];
    const float* d2_ob = (const float*)d_in[30];
    const float* fc_w  = (const float*)d_in[31];
    const float* fc_b  = (const float*)d_in[32];

    float* pre    = (float*)d_ws;                                   // 256*15*1000 f32 = 15.36 MB
    float* pooled = (float*)((char*)d_ws + (size_t)256 * 15 * 1000 * 4); // 256*15*40 f32

    k_stem_spatial<<<dim3(4, 256), 256, 0, stream>>>(
        x, stem_w, stem_g, stem_b, b1_sw, b2_sw, b3_sw, pre);

    k_branch_row<<<3840, 256, 0, stream>>>(
        pre,
        b1_g1, b1_b1, b1_tw, b1_g2, b1_b2,
        b2_g1, b2_b1, b2_tw, b2_g2, b2_b2,
        b3_g1, b3_b1, b3_tw, b3_g2, b3_b2,
        pooled);

    k_head<<<256, 64, 0, stream>>>(
        pooled, pw_w, pw_g, pw_b,
        d1_w, d1_ow, d1_ob, d2_w, d2_ow, d2_ob,
        fc_w, fc_b, (float*)d_out);
}